// Round 19
// baseline (230.716 us; speedup 1.0000x reference)
//
#include <hip/hip_runtime.h>
#include <math.h>

typedef __bf16 bf16x8 __attribute__((ext_vector_type(8)));
typedef float f32x4 __attribute__((ext_vector_type(4)));
typedef float f32x2 __attribute__((ext_vector_type(2)));

#define NVIEWS 4
#define RESN 64
#define PP 4096
#define NRAYS (NVIEWS * PP)
#define FEATC 32
#define PRES 256
#define NSAMP 92
#define STEPF ((2.7f - 1.0f) / 92.0f)
#define FOVF 0.8575560548920328f

#define NW 8                  // waves per block, 1 ray per wave
#define TPB (NW * 64)         // 512 threads
#define HPAD2 72              // hb row stride (bf16), 144B mult of 16 (and of 8)

#define NPLANE ((size_t)NVIEWS * 3 * PRES * PRES * FEATC)   // f32 elems

// -------- transpose planes (v,pl,c,y,x) -> (v,pl,y,x,c) --------
__global__ __launch_bounds__(PRES) void transpose_planes(
    const float* __restrict__ in, float* __restrict__ out) {
  int b  = blockIdx.x;          // vp*256 + y
  int vp = b >> 8;
  int y  = b & 255;
  int x  = threadIdx.x;
  const float* src = in + (size_t)vp * FEATC * PRES * PRES + (size_t)y * PRES + x;
  float* dst = out + (((size_t)vp * PRES + y) * PRES + x) * FEATC;
  float v[FEATC];
#pragma unroll
  for (int c = 0; c < FEATC; ++c) v[c] = src[(size_t)c * PRES * PRES];
#pragma unroll
  for (int q = 0; q < FEATC / 4; ++q) {
    float4 t = make_float4(v[q * 4 + 0], v[q * 4 + 1], v[q * 4 + 2], v[q * 4 + 3]);
    *reinterpret_cast<float4*>(dst + q * 4) = t;
  }
}

__device__ __forceinline__ unsigned short f2bf(float x) {
  unsigned int u = __float_as_uint(x);
  u += 0x7fffu + ((u >> 16) & 1u);
  return (unsigned short)(u >> 16);
}
__device__ __forceinline__ f32x2 mk2(float a, float b) { f32x2 r; r[0] = a; r[1] = b; return r; }

// -------- waveized render: 1 ray/wave; swapped GEMM1/GEMM3 (packed b64 epilogues) --------
// Swap trick: h^T = W1^T · feat^T. B-frag(feat^T) == our A-frag gather (fv, unchanged);
// A-frag(W1^T) == the SAME wlds entry as B-frag(W1) with nt->mt (index-verified).
// C-layout of h^T gives each lane 4 CONSECUTIVE h-cols -> 8 packed ds_write_b64
// instead of 32 scalar ds_write_b16. Same for GEMM3/hr. GEMM2/4 unchanged.
// DS inst/iter ~106 -> ~57. LDS weight table kept (r18: global frags regressed,
// 200cy load latency entered the serial chain; LDS ~10cy reads don't).
// LDS budget rule (r13): <= ~72KB/block for 2 blocks/CU; here 63.5KB.
// NOTE: __launch_bounds__(.,4) forces a 64-VGPR cap -> ~1GB spill (r4-r5). Use (.,2).
template <int TR>
__global__ __launch_bounds__(TPB, 2) void render_wave(
    const float* __restrict__ c2w, const float* __restrict__ planes,
    const float* __restrict__ background, const float* __restrict__ t_jitter,
    const float* __restrict__ W1, const float* __restrict__ b1,
    const float* __restrict__ W2, const float* __restrict__ b2,
    const float* __restrict__ Wr1, const float* __restrict__ br1,
    const float* __restrict__ Wr2, const float* __restrict__ br2,
    float* __restrict__ out) {
  // frag f in [0,20): 0..11 = W1[ks*4+n]; 12..13 = W2[ks]; 14..17 = R1[n]; 18..19 = R2[ks]
  __shared__ __bf16 wlds[20 * 64 * 8];      // 20.0 KB block-shared weight frags
  __shared__ __bf16 hbA[NW][32][HPAD2];     // 36.0 KB: h -> colorA(cols0..17) -> hr
  __shared__ float alphaA[NW][96];          // 3.0 KB raw sigma logits
  __shared__ __bf16 rgbA[NW][96 * 3];       // 4.5 KB raw rgb logits (bf16, r13/r18-proven)

  const int tid = threadIdx.x;
  const int w = tid >> 6;        // wave 0..NW-1
  const int lane = tid & 63;
  const int lr = lane & 15;
  const int lg = lane >> 4;

  __bf16 (*hb)[HPAD2] = hbA[w];
  float* alphaL = alphaA[w];
  __bf16* rgbL = rgbA[w];

  // ---- stage weight fragments into LDS ----
  for (int slot = tid; slot < 20 * 64; slot += TPB) {
    const int f = slot >> 6, l = slot & 63;
    const int flr = l & 15, flg = l >> 4;
    union { unsigned short u[8]; bf16x8 b; } t;
    if (f < 12) {
      const int ks = f >> 2, nt = f & 3;
#pragma unroll
      for (int i = 0; i < 8; ++i)
        t.u[i] = f2bf(W1[(ks * 32 + flg * 8 + i) * 64 + nt * 16 + flr]);
    } else if (f < 14) {
      const int ks = f - 12;
#pragma unroll
      for (int i = 0; i < 8; ++i)
        t.u[i] = f2bf(W2[(ks * 32 + flg * 8 + i) * 16 + flr]);
    } else if (f < 18) {
      const int nt = f - 14;
#pragma unroll
      for (int i = 0; i < 8; ++i) {
        const int k = flg * 8 + i;
        t.u[i] = (k < 18) ? f2bf(Wr1[k * 64 + nt * 16 + flr]) : (unsigned short)0;
      }
    } else {
      const int ks = f - 18;
#pragma unroll
      for (int i = 0; i < 8; ++i)
        t.u[i] = (flr < 3) ? f2bf(Wr2[(ks * 32 + flg * 8 + i) * 3 + flr]) : (unsigned short)0;
    }
    *(bf16x8*)&wlds[slot * 8] = t.b;
  }

  // per-lane bias vectors: GEMM1/GEMM3 epilogues need b[mt*16 + lg*4 + r]
  float4 b1q[4], br1q[4];
#pragma unroll
  for (int mt = 0; mt < 4; ++mt) {
    b1q[mt]  = *(const float4*)&b1[mt * 16 + lg * 4];
    br1q[mt] = *(const float4*)&br1[mt * 16 + lg * 4];
  }
  const float b2v = b2[lr];
  const float br2v = (lr < 3) ? br2[lr] : 0.f;

  // ---- ray setup (wave-uniform) ----
  const int ray = blockIdx.x * NW + w;       // NRAYS % NW == 0: no tail
  const int view = ray >> 12;
  const int p = ray & 4095;
  const float foc = 0.5f * (float)RESN / tanf(FOVF * 0.5f);
  const float dxn = ((float)(p & 63) + 0.5f - 32.f) / foc;
  const float dyn = ((float)(p >> 6) + 0.5f - 32.f) / foc;
  const float* M = c2w + view * 16;
  const float rdx = M[0] * dxn + M[1] * dyn + M[2];
  const float rdy = M[4] * dxn + M[5] * dyn + M[6];
  const float rdz = M[8] * dxn + M[9] * dyn + M[10];
  const float rox = M[3] + 0.5f, roy = M[7] + 0.5f, roz = M[11] + 0.5f;
  const unsigned int dirxy = (unsigned int)f2bf(rdx) | ((unsigned int)f2bf(rdy) << 16);
  const unsigned short dirz = f2bf(rdz);

  __syncthreads();   // weight table ready (only block barrier)

  const __bf16* wl = wlds + lane * 8;   // lane-fixed base; frag f at +f*512 elems

  for (int iter = 0; iter < 3; ++iter) {
    // ---- per-lane positions for its two sample rows (s0=lr, s1=lr+16) ----
    float pxr[2], pyr[2], pzr[2];
#pragma unroll
    for (int rowi = 0; rowi < 2; ++rowi) {
      const int s = iter * 32 + lr + rowi * 16;
      const int sj = (s < NSAMP) ? s : (NSAMP - 1);
      const float jit = t_jitter[(size_t)ray * NSAMP + sj];
      const float t = 1.0f + ((float)s + jit) * STEPF + STEPF * 0.5f;
      pxr[rowi] = fminf(fmaxf(rox + rdx * t, 0.f), 1.f);
      pyr[rowi] = fminf(fmaxf(roy + rdy * t, 0.f), 1.f);
      pzr[rowi] = fminf(fmaxf(roz + rdz * t, 0.f), 1.f);
    }

    // ---- gather feat frags: fv[pl][nt] = B-frag of feat^T (== A-frag of feat) ----
    bf16x8 fv[3][2];
#pragma unroll
    for (int pl = 0; pl < 3; ++pl) {
#pragma unroll
      for (int rowi = 0; rowi < 2; ++rowi) {
        const float uu = (pl == 2) ? pyr[rowi] : pxr[rowi];
        const float vv = (pl == 0) ? pyr[rowi] : pzr[rowi];
        const float xf = uu * 255.f, yf = vv * 255.f;
        const float x0f = floorf(xf), y0f = floorf(yf);
        const float wx = xf - x0f, wy = yf - y0f;
        const int x0 = (int)x0f, y0 = (int)y0f;
        const int x1 = min(x0 + 1, 255), y1 = min(y0 + 1, 255);
        const float w00 = (1.f - wx) * (1.f - wy), w01 = wx * (1.f - wy);
        const float w10 = (1.f - wx) * wy, w11 = wx * wy;
        f32x2 fp[4];
        if (TR) {
          const unsigned int slab = (unsigned int)(view * 3 + pl) * (PRES * PRES * FEATC);
          const unsigned int o00 = slab + ((unsigned int)(y0 * 256 + x0) << 5) + (lg << 3);
          const unsigned int dx32 = (unsigned int)(x1 - x0) << 5;
          const unsigned int dy32 = (unsigned int)(y1 - y0) << 13;
          const float4 A0 = *(const float4*)(planes + o00);
          const float4 A1 = *(const float4*)(planes + o00 + 4);
          const float4 B0 = *(const float4*)(planes + (o00 + dx32));
          const float4 B1 = *(const float4*)(planes + (o00 + dx32) + 4);
          const float4 C0 = *(const float4*)(planes + (o00 + dy32));
          const float4 C1 = *(const float4*)(planes + (o00 + dy32) + 4);
          const float4 D0 = *(const float4*)(planes + (o00 + dx32 + dy32));
          const float4 D1 = *(const float4*)(planes + (o00 + dx32 + dy32) + 4);
          fp[0] = mk2(A0.x, A0.y) * w00 + mk2(B0.x, B0.y) * w01 +
                  mk2(C0.x, C0.y) * w10 + mk2(D0.x, D0.y) * w11;
          fp[1] = mk2(A0.z, A0.w) * w00 + mk2(B0.z, B0.w) * w01 +
                  mk2(C0.z, C0.w) * w10 + mk2(D0.z, D0.w) * w11;
          fp[2] = mk2(A1.x, A1.y) * w00 + mk2(B1.x, B1.y) * w01 +
                  mk2(C1.x, C1.y) * w10 + mk2(D1.x, D1.y) * w11;
          fp[3] = mk2(A1.z, A1.w) * w00 + mk2(B1.z, B1.w) * w01 +
                  mk2(C1.z, C1.w) * w10 + mk2(D1.z, D1.w) * w11;
        } else {
          const float* pb = planes + (size_t)(view * 3 + pl) * (FEATC * PRES * PRES);
          const int o00 = y0 * 256 + x0, o01 = y0 * 256 + x1;
          const int o10 = y1 * 256 + x0, o11 = y1 * 256 + x1;
          float f[8];
#pragma unroll
          for (int c = 0; c < 8; ++c) {
            const float* pc = pb + (size_t)(lg * 8 + c) * (PRES * PRES);
            f[c] = pc[o00] * w00 + pc[o01] * w01 + pc[o10] * w10 + pc[o11] * w11;
          }
#pragma unroll
          for (int j = 0; j < 4; ++j) fp[j] = mk2(f[2 * j], f[2 * j + 1]);
        }
        bf16x8 vfr;
#pragma unroll
        for (int j = 0; j < 4; ++j) { vfr[2 * j] = (__bf16)fp[j][0]; vfr[2 * j + 1] = (__bf16)fp[j][1]; }
        fv[pl][rowi] = vfr;
      }
    }

    // ---- GEMM1 (SWAPPED): h^T = W1^T @ feat^T; packed b64 h-writes ----
    // A-frag(W1^T)[mt][pl] = wlds frag (pl*4+mt); lane l: W1[pl*32+lg*8+i][mt*16+lr]
    // D: lane holds h[nt*16+lr][mt*16+lg*4 + r] -> 4 consecutive h-cols -> b64
#pragma unroll
    for (int mt = 0; mt < 4; ++mt) {
      f32x4 acc[2] = {};
#pragma unroll
      for (int pl = 0; pl < 3; ++pl) {
        const bf16x8 aw = *(const bf16x8*)(wl + (pl * 4 + mt) * 512);
#pragma unroll
        for (int nt = 0; nt < 2; ++nt)
          acc[nt] = __builtin_amdgcn_mfma_f32_16x16x32_bf16(aw, fv[pl][nt], acc[nt], 0, 0, 0);
      }
      const float4 bq = b1q[mt];
#pragma unroll
      for (int nt = 0; nt < 2; ++nt) {
        uint2 v;
        v.x = (unsigned int)f2bf(fmaxf(acc[nt][0] + bq.x, 0.f)) |
              ((unsigned int)f2bf(fmaxf(acc[nt][1] + bq.y, 0.f)) << 16);
        v.y = (unsigned int)f2bf(fmaxf(acc[nt][2] + bq.z, 0.f)) |
              ((unsigned int)f2bf(fmaxf(acc[nt][3] + bq.w, 0.f)) << 16);
        *(uint2*)&hb[nt * 16 + lr][mt * 16 + lg * 4] = v;   // 8B-aligned b64
      }
    }

    // ---- GEMM2 (unswapped): o = h @ W2 (64->16) ----
    f32x4 acc2[2] = {};
    {
      const bf16x8 bw0 = *(const bf16x8*)(wl + 12 * 512);
      const bf16x8 bw1 = *(const bf16x8*)(wl + 13 * 512);
#pragma unroll
      for (int mt = 0; mt < 2; ++mt) {
        const bf16x8 a0 = *(const bf16x8*)&hb[mt * 16 + lr][lg * 8];
        const bf16x8 a1 = *(const bf16x8*)&hb[mt * 16 + lr][32 + lg * 8];
        acc2[mt] = __builtin_amdgcn_mfma_f32_16x16x32_bf16(a0, bw0, acc2[mt], 0, 0, 0);
        acc2[mt] = __builtin_amdgcn_mfma_f32_16x16x32_bf16(a1, bw1, acc2[mt], 0, 0, 0);
      }
    }
    // epilogue: raw sigma -> alphaL; dir -> hb cols 0..2; geo -> hb cols 3..17
#pragma unroll
    for (int mt = 0; mt < 2; ++mt)
#pragma unroll
      for (int r = 0; r < 4; ++r) {
        const int m = mt * 16 + lg * 4 + r;
        const int s2 = iter * 32 + m;
        const float val = acc2[mt][r] + b2v;
        if (lr == 0) {
          alphaL[s2] = val;
          *(unsigned int*)&hb[m][0] = dirxy;
          *(unsigned short*)&hb[m][2] = dirz;
        } else {
          hb[m][2 + lr] = (__bf16)val;   // geo i=lr-1 -> col 3+(lr-1)
        }
      }

    // ---- GEMM3 (SWAPPED): hr^T = Wr1^T @ colorA^T; packed b64 hr-writes ----
    {
      bf16x8 ca[2];
#pragma unroll
      for (int nt = 0; nt < 2; ++nt)
        ca[nt] = *(const bf16x8*)&hb[nt * 16 + lr][lg * 8];   // B-frag(colorA^T)
#pragma unroll
      for (int mt = 0; mt < 4; ++mt) {
        const bf16x8 aw = *(const bf16x8*)(wl + (14 + mt) * 512);
        f32x4 acc[2] = {};
#pragma unroll
        for (int nt = 0; nt < 2; ++nt)
          acc[nt] = __builtin_amdgcn_mfma_f32_16x16x32_bf16(aw, ca[nt], acc[nt], 0, 0, 0);
        const float4 bq = br1q[mt];
        // hr writes follow the ca[] reads in program order (may-alias LDS) -> safe
#pragma unroll
        for (int nt = 0; nt < 2; ++nt) {
          uint2 v;
          v.x = (unsigned int)f2bf(fmaxf(acc[nt][0] + bq.x, 0.f)) |
                ((unsigned int)f2bf(fmaxf(acc[nt][1] + bq.y, 0.f)) << 16);
          v.y = (unsigned int)f2bf(fmaxf(acc[nt][2] + bq.z, 0.f)) |
                ((unsigned int)f2bf(fmaxf(acc[nt][3] + bq.w, 0.f)) << 16);
          *(uint2*)&hb[nt * 16 + lr][mt * 16 + lg * 4] = v;
        }
      }
    }

    // ---- GEMM4 (unswapped): hr @ Wr2pad -> raw rgb logits (bf16) ----
    f32x4 acc4[2] = {};
    {
      const bf16x8 bw0 = *(const bf16x8*)(wl + 18 * 512);
      const bf16x8 bw1 = *(const bf16x8*)(wl + 19 * 512);
#pragma unroll
      for (int mt = 0; mt < 2; ++mt) {
        const bf16x8 a0 = *(const bf16x8*)&hb[mt * 16 + lr][lg * 8];
        const bf16x8 a1 = *(const bf16x8*)&hb[mt * 16 + lr][32 + lg * 8];
        acc4[mt] = __builtin_amdgcn_mfma_f32_16x16x32_bf16(a0, bw0, acc4[mt], 0, 0, 0);
        acc4[mt] = __builtin_amdgcn_mfma_f32_16x16x32_bf16(a1, bw1, acc4[mt], 0, 0, 0);
      }
    }
#pragma unroll
    for (int mt = 0; mt < 2; ++mt)
#pragma unroll
      for (int r = 0; r < 4; ++r) {
        const int m = mt * 16 + lg * 4 + r;
        const int s2 = iter * 32 + m;
        if (lr < 3) rgbL[s2 * 3 + lr] = (__bf16)(acc4[mt][r] + br2v);
      }
  }

  // ---- per-wave composite with inline activations ----
  {
    const float o0 = alphaL[lane];
    const float sp = fmaxf(o0, 0.f) + log1pf(__expf(-fabsf(o0)));
    const float a = 1.f - __expf(-sp * STEPF);
    float r0 = (float)rgbL[lane * 3 + 0], r1 = (float)rgbL[lane * 3 + 1], r2 = (float)rgbL[lane * 3 + 2];
    r0 = 1.f / (1.f + __expf(-r0));
    r1 = 1.f / (1.f + __expf(-r1));
    r2 = 1.f / (1.f + __expf(-r2));
    float q = 1.f - a + 1e-10f;
#pragma unroll
    for (int d = 1; d < 64; d <<= 1) { const float t = __shfl_up(q, d); if (lane >= d) q *= t; }
    float T = __shfl_up(q, 1);
    if (lane == 0) T = 1.f;
    const float wgt = T * a;
    float cr = wgt * r0, cg = wgt * r1, cb = wgt * r2, accA = wgt;
    const float Ttot = __shfl(q, 63);
    float a2 = 0.f, s0 = 0.f, s1 = 0.f, s2c = 0.f;
    if (lane < 28) {
      const int i2 = 64 + lane;
      const float o0b = alphaL[i2];
      const float spb = fmaxf(o0b, 0.f) + log1pf(__expf(-fabsf(o0b)));
      a2 = 1.f - __expf(-spb * STEPF);
      s0 = 1.f / (1.f + __expf(-(float)rgbL[i2 * 3 + 0]));
      s1 = 1.f / (1.f + __expf(-(float)rgbL[i2 * 3 + 1]));
      s2c = 1.f / (1.f + __expf(-(float)rgbL[i2 * 3 + 2]));
    }
    float q2 = 1.f - a2 + 1e-10f;
#pragma unroll
    for (int d = 1; d < 64; d <<= 1) { const float t = __shfl_up(q2, d); if (lane >= d) q2 *= t; }
    float T2 = __shfl_up(q2, 1);
    if (lane == 0) T2 = 1.f;
    T2 *= Ttot;
    if (lane < 28) {
      const float w2 = T2 * a2;
      cr += w2 * s0; cg += w2 * s1; cb += w2 * s2c;
      accA += w2;
    }
#pragma unroll
    for (int d = 32; d; d >>= 1) {
      cr += __shfl_xor(cr, d); cg += __shfl_xor(cg, d);
      cb += __shfl_xor(cb, d); accA += __shfl_xor(accA, d);
    }
    if (lane == 0) {
      const float* bg = background + view * 3;
      float* po = out + (size_t)ray * 3;
      po[0] = cr + (1.f - accA) * bg[0];
      po[1] = cg + (1.f - accA) * bg[1];
      po[2] = cb + (1.f - accA) * bg[2];
    }
  }
}

extern "C" void kernel_launch(void* const* d_in, const int* in_sizes, int n_in,
                              void* d_out, int out_size, void* d_ws, size_t ws_size,
                              hipStream_t stream) {
  const float* c2w        = (const float*)d_in[0];
  const float* planes     = (const float*)d_in[1];
  const float* background = (const float*)d_in[2];
  const float* t_jitter   = (const float*)d_in[3];
  const float* W1  = (const float*)d_in[4];
  const float* b1  = (const float*)d_in[5];
  const float* W2  = (const float*)d_in[6];
  const float* b2  = (const float*)d_in[7];
  const float* Wr1 = (const float*)d_in[8];
  const float* br1 = (const float*)d_in[9];
  const float* Wr2 = (const float*)d_in[10];
  const float* br2 = (const float*)d_in[11];
  float* out = (float*)d_out;

  const int n_blocks = NRAYS / NW;   // 2048 blocks, 1 ray per wave
  const size_t tr_bytes = NPLANE * sizeof(float);

  if (ws_size >= tr_bytes) {
    float* tp = (float*)d_ws;
    transpose_planes<<<NVIEWS * 3 * PRES, PRES, 0, stream>>>(planes, tp);
    render_wave<1><<<n_blocks, TPB, 0, stream>>>(
        c2w, tp, background, t_jitter, W1, b1, W2, b2, Wr1, br1, Wr2, br2, out);
  } else {
    render_wave<0><<<n_blocks, TPB, 0, stream>>>(
        c2w, planes, background, t_jitter, W1, b1, W2, b2, Wr1, br1, Wr2, br2, out);
  }
}

// Round 20
// 192.259 us; speedup vs baseline: 1.2000x; 1.2000x over previous
//
#include <hip/hip_runtime.h>
#include <math.h>

typedef __bf16 bf16x8 __attribute__((ext_vector_type(8)));
typedef float f32x4 __attribute__((ext_vector_type(4)));
typedef float f32x2 __attribute__((ext_vector_type(2)));

#define NVIEWS 4
#define RESN 64
#define PP 4096
#define NRAYS (NVIEWS * PP)
#define FEATC 32
#define PRES 256
#define NSAMP 92
#define STEPF ((2.7f - 1.0f) / 92.0f)
#define FOVF 0.8575560548920328f

#define NW 8                  // waves per block, 1 ray per wave
#define TPB (NW * 64)         // 512 threads
#define HPAD2 72              // hb row stride (bf16), 144B mult of 16

#define NPLANE ((size_t)NVIEWS * 3 * PRES * PRES * FEATC)   // f32 elems

// -------- transpose planes (v,pl,c,y,x) -> (v,pl,y,x,c) --------
__global__ __launch_bounds__(PRES) void transpose_planes(
    const float* __restrict__ in, float* __restrict__ out) {
  int b  = blockIdx.x;          // vp*256 + y
  int vp = b >> 8;
  int y  = b & 255;
  int x  = threadIdx.x;
  const float* src = in + (size_t)vp * FEATC * PRES * PRES + (size_t)y * PRES + x;
  float* dst = out + (((size_t)vp * PRES + y) * PRES + x) * FEATC;
  float v[FEATC];
#pragma unroll
  for (int c = 0; c < FEATC; ++c) v[c] = src[(size_t)c * PRES * PRES];
#pragma unroll
  for (int q = 0; q < FEATC / 4; ++q) {
    float4 t = make_float4(v[q * 4 + 0], v[q * 4 + 1], v[q * 4 + 2], v[q * 4 + 3]);
    *reinterpret_cast<float4*>(dst + q * 4) = t;
  }
}

__device__ __forceinline__ unsigned short f2bf(float x) {
  unsigned int u = __float_as_uint(x);
  u += 0x7fffu + ((u >> 16) & 1u);
  return (unsigned short)(u >> 16);
}
__device__ __forceinline__ f32x2 mk2(float a, float b) { f32x2 r; r[0] = a; r[1] = b; return r; }

// -------- waveized render: 1 ray/wave; B-frags in block LDS; no wave fences --------
// Best-measured configuration (r17: 166.0us kernel, 37% occupancy, VGPR 64).
// Design ledger (r1-r19):
//  - MFMA for all 4 MLP GEMMs; A-frags gathered directly into registers.
//  - Weight B-frags in a 20KB block-shared LDS table (global frags: r18 REGRESSED,
//    ~200cy load latency enters the serial chain; LDS ~10cy reads do not).
//  - LDS <= ~69.6KB/block for 2 blocks/CU (r13: 76.2KB -> 1 block/CU, 23% occ).
//  - No wave-internal fences: wave-private hb/alpha/rgb + in-order DS + compiler
//    counted lgkmcnt suffice (r13/r17-proven; neutral perf, correct).
//  - Scalar b16 epilogue writes; swapped-GEMM packed b64 writes REGRESSED
//    (r19: +48 VGPR, 2.6x bank conflicts).
//  - __launch_bounds__(.,4) forces a 64-VGPR cap -> ~1GB spill (r4-r5). Use (.,2).
template <int TR>
__global__ __launch_bounds__(TPB, 2) void render_wave(
    const float* __restrict__ c2w, const float* __restrict__ planes,
    const float* __restrict__ background, const float* __restrict__ t_jitter,
    const float* __restrict__ W1, const float* __restrict__ b1,
    const float* __restrict__ W2, const float* __restrict__ b2,
    const float* __restrict__ Wr1, const float* __restrict__ br1,
    const float* __restrict__ Wr2, const float* __restrict__ br2,
    float* __restrict__ out) {
  // frag f in [0,20): 0..11 = W1[ks*4+nt]; 12..13 = W2[ks]; 14..17 = R1[nt]; 18..19 = R2[ks]
  __shared__ __bf16 wlds[20 * 64 * 8];      // 20.0 KB block-shared B-frags
  __shared__ __bf16 hbA[NW][32][HPAD2];     // 36.0 KB: h -> colorA(cols0..17) -> hr
  __shared__ float alphaA[NW][96];          // 3.0 KB raw sigma logits
  __shared__ float rgbA[NW][96 * 3];        // 9.0 KB raw rgb logits
  // total 68.0 KB -> 2 blocks/CU

  const int tid = threadIdx.x;
  const int w = tid >> 6;        // wave 0..NW-1
  const int lane = tid & 63;
  const int lr = lane & 15;
  const int lg = lane >> 4;

  __bf16 (*hb)[HPAD2] = hbA[w];
  float* alphaL = alphaA[w];
  float* rgbL = rgbA[w];

  // ---- stage B-fragments into LDS ----
  for (int slot = tid; slot < 20 * 64; slot += TPB) {
    const int f = slot >> 6, l = slot & 63;
    const int flr = l & 15, flg = l >> 4;
    union { unsigned short u[8]; bf16x8 b; } t;
    if (f < 12) {
      const int ks = f >> 2, nt = f & 3;
#pragma unroll
      for (int i = 0; i < 8; ++i)
        t.u[i] = f2bf(W1[(ks * 32 + flg * 8 + i) * 64 + nt * 16 + flr]);
    } else if (f < 14) {
      const int ks = f - 12;
#pragma unroll
      for (int i = 0; i < 8; ++i)
        t.u[i] = f2bf(W2[(ks * 32 + flg * 8 + i) * 16 + flr]);
    } else if (f < 18) {
      const int nt = f - 14;
#pragma unroll
      for (int i = 0; i < 8; ++i) {
        const int k = flg * 8 + i;
        t.u[i] = (k < 18) ? f2bf(Wr1[k * 64 + nt * 16 + flr]) : (unsigned short)0;
      }
    } else {
      const int ks = f - 18;
#pragma unroll
      for (int i = 0; i < 8; ++i)
        t.u[i] = (flr < 3) ? f2bf(Wr2[(ks * 32 + flg * 8 + i) * 3 + flr]) : (unsigned short)0;
    }
    *(bf16x8*)&wlds[slot * 8] = t.b;
  }

  float b1v[4], br1v[4];
#pragma unroll
  for (int nt = 0; nt < 4; ++nt) { b1v[nt] = b1[nt * 16 + lr]; br1v[nt] = br1[nt * 16 + lr]; }
  const float b2v = b2[lr];
  const float br2v = (lr < 3) ? br2[lr] : 0.f;

  // ---- ray setup (wave-uniform) ----
  const int ray = blockIdx.x * NW + w;       // NRAYS % NW == 0: no tail
  const int view = ray >> 12;
  const int p = ray & 4095;
  const float foc = 0.5f * (float)RESN / tanf(FOVF * 0.5f);
  const float dxn = ((float)(p & 63) + 0.5f - 32.f) / foc;
  const float dyn = ((float)(p >> 6) + 0.5f - 32.f) / foc;
  const float* M = c2w + view * 16;
  const float rdx = M[0] * dxn + M[1] * dyn + M[2];
  const float rdy = M[4] * dxn + M[5] * dyn + M[6];
  const float rdz = M[8] * dxn + M[9] * dyn + M[10];
  const float rox = M[3] + 0.5f, roy = M[7] + 0.5f, roz = M[11] + 0.5f;
  const unsigned int dirxy = (unsigned int)f2bf(rdx) | ((unsigned int)f2bf(rdy) << 16);
  const unsigned short dirz = f2bf(rdz);

  __syncthreads();   // weight table ready (only block barrier)

  const __bf16* wl = wlds + lane * 8;   // lane-fixed base; frag f at +f*512 elems

  for (int iter = 0; iter < 3; ++iter) {
    // ---- per-lane positions for its two A-frag rows (m0=lr, m1=lr+16) ----
    float pxr[2], pyr[2], pzr[2];
#pragma unroll
    for (int rowi = 0; rowi < 2; ++rowi) {
      const int s = iter * 32 + lr + rowi * 16;
      const int sj = (s < NSAMP) ? s : (NSAMP - 1);
      const float jit = t_jitter[(size_t)ray * NSAMP + sj];
      const float t = 1.0f + ((float)s + jit) * STEPF + STEPF * 0.5f;
      pxr[rowi] = fminf(fmaxf(rox + rdx * t, 0.f), 1.f);
      pyr[rowi] = fminf(fmaxf(roy + rdy * t, 0.f), 1.f);
      pzr[rowi] = fminf(fmaxf(roz + rdz * t, 0.f), 1.f);
    }

    // ---- build GEMM1 A-frags in registers (32-bit saddr-friendly offsets) ----
    bf16x8 fv[3][2];
#pragma unroll
    for (int pl = 0; pl < 3; ++pl) {
#pragma unroll
      for (int rowi = 0; rowi < 2; ++rowi) {
        const float uu = (pl == 2) ? pyr[rowi] : pxr[rowi];
        const float vv = (pl == 0) ? pyr[rowi] : pzr[rowi];
        const float xf = uu * 255.f, yf = vv * 255.f;
        const float x0f = floorf(xf), y0f = floorf(yf);
        const float wx = xf - x0f, wy = yf - y0f;
        const int x0 = (int)x0f, y0 = (int)y0f;
        const int x1 = min(x0 + 1, 255), y1 = min(y0 + 1, 255);
        const float w00 = (1.f - wx) * (1.f - wy), w01 = wx * (1.f - wy);
        const float w10 = (1.f - wx) * wy, w11 = wx * wy;
        f32x2 fp[4];
        if (TR) {
          // uint offsets: slab (<=96MB) + tap deltas; keeps addr math 32-bit
          const unsigned int slab = (unsigned int)(view * 3 + pl) * (PRES * PRES * FEATC);
          const unsigned int o00 = slab + ((unsigned int)(y0 * 256 + x0) << 5) + (lg << 3);
          const unsigned int dx32 = (unsigned int)(x1 - x0) << 5;
          const unsigned int dy32 = (unsigned int)(y1 - y0) << 13;
          const float4 A0 = *(const float4*)(planes + o00);
          const float4 A1 = *(const float4*)(planes + o00 + 4);
          const float4 B0 = *(const float4*)(planes + (o00 + dx32));
          const float4 B1 = *(const float4*)(planes + (o00 + dx32) + 4);
          const float4 C0 = *(const float4*)(planes + (o00 + dy32));
          const float4 C1 = *(const float4*)(planes + (o00 + dy32) + 4);
          const float4 D0 = *(const float4*)(planes + (o00 + dx32 + dy32));
          const float4 D1 = *(const float4*)(planes + (o00 + dx32 + dy32) + 4);
          fp[0] = mk2(A0.x, A0.y) * w00 + mk2(B0.x, B0.y) * w01 +
                  mk2(C0.x, C0.y) * w10 + mk2(D0.x, D0.y) * w11;
          fp[1] = mk2(A0.z, A0.w) * w00 + mk2(B0.z, B0.w) * w01 +
                  mk2(C0.z, C0.w) * w10 + mk2(D0.z, D0.w) * w11;
          fp[2] = mk2(A1.x, A1.y) * w00 + mk2(B1.x, B1.y) * w01 +
                  mk2(C1.x, C1.y) * w10 + mk2(D1.x, D1.y) * w11;
          fp[3] = mk2(A1.z, A1.w) * w00 + mk2(B1.z, B1.w) * w01 +
                  mk2(C1.z, C1.w) * w10 + mk2(D1.z, D1.w) * w11;
        } else {
          const float* pb = planes + (size_t)(view * 3 + pl) * (FEATC * PRES * PRES);
          const int o00 = y0 * 256 + x0, o01 = y0 * 256 + x1;
          const int o10 = y1 * 256 + x0, o11 = y1 * 256 + x1;
          float f[8];
#pragma unroll
          for (int c = 0; c < 8; ++c) {
            const float* pc = pb + (size_t)(lg * 8 + c) * (PRES * PRES);
            f[c] = pc[o00] * w00 + pc[o01] * w01 + pc[o10] * w10 + pc[o11] * w11;
          }
#pragma unroll
          for (int j = 0; j < 4; ++j) fp[j] = mk2(f[2 * j], f[2 * j + 1]);
        }
        bf16x8 vfr;
#pragma unroll
        for (int j = 0; j < 4; ++j) { vfr[2 * j] = (__bf16)fp[j][0]; vfr[2 * j + 1] = (__bf16)fp[j][1]; }
        fv[pl][rowi] = vfr;
      }
    }

    // ---- GEMM1 (nt-outer, 8 acc regs): h = relu(feat @ W1 + b1) -> hb cols 0..63 ----
#pragma unroll
    for (int nt = 0; nt < 4; ++nt) {
      f32x4 acc[2] = {};
#pragma unroll
      for (int pl = 0; pl < 3; ++pl) {
        const bf16x8 bw = *(const bf16x8*)(wl + (pl * 4 + nt) * 512);
#pragma unroll
        for (int mt = 0; mt < 2; ++mt)
          acc[mt] = __builtin_amdgcn_mfma_f32_16x16x32_bf16(fv[pl][mt], bw, acc[mt], 0, 0, 0);
      }
#pragma unroll
      for (int mt = 0; mt < 2; ++mt)
#pragma unroll
        for (int r = 0; r < 4; ++r)
          hb[mt * 16 + lg * 4 + r][nt * 16 + lr] = (__bf16)fmaxf(acc[mt][r] + b1v[nt], 0.f);
    }

    // ---- GEMM2: h @ W2 (64->16) ----
    f32x4 acc2[2] = {};
    {
      const bf16x8 bw0 = *(const bf16x8*)(wl + 12 * 512);
      const bf16x8 bw1 = *(const bf16x8*)(wl + 13 * 512);
#pragma unroll
      for (int mt = 0; mt < 2; ++mt) {
        const bf16x8 a0 = *(const bf16x8*)&hb[mt * 16 + lr][lg * 8];
        const bf16x8 a1 = *(const bf16x8*)&hb[mt * 16 + lr][32 + lg * 8];
        acc2[mt] = __builtin_amdgcn_mfma_f32_16x16x32_bf16(a0, bw0, acc2[mt], 0, 0, 0);
        acc2[mt] = __builtin_amdgcn_mfma_f32_16x16x32_bf16(a1, bw1, acc2[mt], 0, 0, 0);
      }
    }
    // epilogue: raw sigma -> alphaL; dir -> hb cols 0..2; geo -> hb cols 3..17
    // (writes issue after GEMM2's reads in same-wave DS order -> safe)
#pragma unroll
    for (int mt = 0; mt < 2; ++mt)
#pragma unroll
      for (int r = 0; r < 4; ++r) {
        const int m = mt * 16 + lg * 4 + r;
        const int s2 = iter * 32 + m;
        const float val = acc2[mt][r] + b2v;
        if (lr == 0) {
          alphaL[s2] = val;
          *(unsigned int*)&hb[m][0] = dirxy;
          *(unsigned short*)&hb[m][2] = dirz;
        } else {
          hb[m][2 + lr] = (__bf16)val;   // geo i=lr-1 -> col 3+(lr-1)
        }
      }

    // ---- GEMM3: colorA[32x32] @ Wr1pad (cols 18..31 stale-h x zero weights) ----
    {
      bf16x8 a[2];
#pragma unroll
      for (int mt = 0; mt < 2; ++mt) a[mt] = *(const bf16x8*)&hb[mt * 16 + lr][lg * 8];
#pragma unroll
      for (int nt = 0; nt < 4; ++nt) {
        const bf16x8 bw = *(const bf16x8*)(wl + (14 + nt) * 512);
        f32x4 acc[2] = {};
#pragma unroll
        for (int mt = 0; mt < 2; ++mt)
          acc[mt] = __builtin_amdgcn_mfma_f32_16x16x32_bf16(a[mt], bw, acc[mt], 0, 0, 0);
        // hr writes follow the a[] reads in DS order (same-wave FIFO) -> safe
#pragma unroll
        for (int mt = 0; mt < 2; ++mt)
#pragma unroll
          for (int r = 0; r < 4; ++r)
            hb[mt * 16 + lg * 4 + r][nt * 16 + lr] = (__bf16)fmaxf(acc[mt][r] + br1v[nt], 0.f);
      }
    }

    // ---- GEMM4: hr @ Wr2pad -> raw rgb logits ----
    f32x4 acc4[2] = {};
    {
      const bf16x8 bw0 = *(const bf16x8*)(wl + 18 * 512);
      const bf16x8 bw1 = *(const bf16x8*)(wl + 19 * 512);
#pragma unroll
      for (int mt = 0; mt < 2; ++mt) {
        const bf16x8 a0 = *(const bf16x8*)&hb[mt * 16 + lr][lg * 8];
        const bf16x8 a1 = *(const bf16x8*)&hb[mt * 16 + lr][32 + lg * 8];
        acc4[mt] = __builtin_amdgcn_mfma_f32_16x16x32_bf16(a0, bw0, acc4[mt], 0, 0, 0);
        acc4[mt] = __builtin_amdgcn_mfma_f32_16x16x32_bf16(a1, bw1, acc4[mt], 0, 0, 0);
      }
    }
#pragma unroll
    for (int mt = 0; mt < 2; ++mt)
#pragma unroll
      for (int r = 0; r < 4; ++r) {
        const int m = mt * 16 + lg * 4 + r;
        const int s2 = iter * 32 + m;
        if (lr < 3) rgbL[s2 * 3 + lr] = acc4[mt][r] + br2v;
      }
  }

  // ---- per-wave composite with inline activations ----
  {
    const float o0 = alphaL[lane];
    const float sp = fmaxf(o0, 0.f) + log1pf(__expf(-fabsf(o0)));
    const float a = 1.f - __expf(-sp * STEPF);
    float r0 = rgbL[lane * 3 + 0], r1 = rgbL[lane * 3 + 1], r2 = rgbL[lane * 3 + 2];
    r0 = 1.f / (1.f + __expf(-r0));
    r1 = 1.f / (1.f + __expf(-r1));
    r2 = 1.f / (1.f + __expf(-r2));
    float q = 1.f - a + 1e-10f;
#pragma unroll
    for (int d = 1; d < 64; d <<= 1) { const float t = __shfl_up(q, d); if (lane >= d) q *= t; }
    float T = __shfl_up(q, 1);
    if (lane == 0) T = 1.f;
    const float wgt = T * a;
    float cr = wgt * r0, cg = wgt * r1, cb = wgt * r2, accA = wgt;
    const float Ttot = __shfl(q, 63);
    float a2 = 0.f, s0 = 0.f, s1 = 0.f, s2c = 0.f;
    if (lane < 28) {
      const int i2 = 64 + lane;
      const float o0b = alphaL[i2];
      const float spb = fmaxf(o0b, 0.f) + log1pf(__expf(-fabsf(o0b)));
      a2 = 1.f - __expf(-spb * STEPF);
      s0 = 1.f / (1.f + __expf(-rgbL[i2 * 3 + 0]));
      s1 = 1.f / (1.f + __expf(-rgbL[i2 * 3 + 1]));
      s2c = 1.f / (1.f + __expf(-rgbL[i2 * 3 + 2]));
    }
    float q2 = 1.f - a2 + 1e-10f;
#pragma unroll
    for (int d = 1; d < 64; d <<= 1) { const float t = __shfl_up(q2, d); if (lane >= d) q2 *= t; }
    float T2 = __shfl_up(q2, 1);
    if (lane == 0) T2 = 1.f;
    T2 *= Ttot;
    if (lane < 28) {
      const float w2 = T2 * a2;
      cr += w2 * s0; cg += w2 * s1; cb += w2 * s2c;
      accA += w2;
    }
#pragma unroll
    for (int d = 32; d; d >>= 1) {
      cr += __shfl_xor(cr, d); cg += __shfl_xor(cg, d);
      cb += __shfl_xor(cb, d); accA += __shfl_xor(accA, d);
    }
    if (lane == 0) {
      const float* bg = background + view * 3;
      float* po = out + (size_t)ray * 3;
      po[0] = cr + (1.f - accA) * bg[0];
      po[1] = cg + (1.f - accA) * bg[1];
      po[2] = cb + (1.f - accA) * bg[2];
    }
  }
}

extern "C" void kernel_launch(void* const* d_in, const int* in_sizes, int n_in,
                              void* d_out, int out_size, void* d_ws, size_t ws_size,
                              hipStream_t stream) {
  const float* c2w        = (const float*)d_in[0];
  const float* planes     = (const float*)d_in[1];
  const float* background = (const float*)d_in[2];
  const float* t_jitter   = (const float*)d_in[3];
  const float* W1  = (const float*)d_in[4];
  const float* b1  = (const float*)d_in[5];
  const float* W2  = (const float*)d_in[6];
  const float* b2  = (const float*)d_in[7];
  const float* Wr1 = (const float*)d_in[8];
  const float* br1 = (const float*)d_in[9];
  const float* Wr2 = (const float*)d_in[10];
  const float* br2 = (const float*)d_in[11];
  float* out = (float*)d_out;

  const int n_blocks = NRAYS / NW;   // 2048 blocks, 1 ray per wave
  const size_t tr_bytes = NPLANE * sizeof(float);

  if (ws_size >= tr_bytes) {
    float* tp = (float*)d_ws;
    transpose_planes<<<NVIEWS * 3 * PRES, PRES, 0, stream>>>(planes, tp);
    render_wave<1><<<n_blocks, TPB, 0, stream>>>(
        c2w, tp, background, t_jitter, W1, b1, W2, b2, Wr1, br1, Wr2, br2, out);
  } else {
    render_wave<0><<<n_blocks, TPB, 0, stream>>>(
        c2w, planes, background, t_jitter, W1, b1, W2, b2, Wr1, br1, Wr2, br2, out);
  }
}

// Round 21
// 134.502 us; speedup vs baseline: 1.7153x; 1.4294x over previous
//
#include <hip/hip_runtime.h>
#include <math.h>

typedef __bf16 bf16x8 __attribute__((ext_vector_type(8)));
typedef float f32x4 __attribute__((ext_vector_type(4)));
typedef float f32x2 __attribute__((ext_vector_type(2)));

#define NVIEWS 4
#define RESN 64
#define PP 4096
#define NRAYS (NVIEWS * PP)
#define FEATC 32
#define PRES 256
#define NSAMP 92
#define STEPF ((2.7f - 1.0f) / 92.0f)
#define FOVF 0.8575560548920328f

#define NW 8                  // waves per block, 1 ray per wave
#define TPB (NW * 64)         // 512 threads
#define HPAD2 72              // hb row stride (bf16), 144B mult of 16

#define NPLANE ((size_t)NVIEWS * 3 * PRES * PRES * FEATC)   // elems

__device__ __forceinline__ unsigned short f2bf(float x) {
  unsigned int u = __float_as_uint(x);
  u += 0x7fffu + ((u >> 16) & 1u);
  return (unsigned short)(u >> 16);
}
__device__ __forceinline__ f32x2 mk2(float a, float b) { f32x2 r; r[0] = a; r[1] = b; return r; }
// unpack 2 packed bf16 -> f32x2 (lo = bits 0..15, hi = bits 16..31)
__device__ __forceinline__ f32x2 bf2f(unsigned int u) {
  f32x2 r;
  r[0] = __uint_as_float(u << 16);
  r[1] = __uint_as_float(u & 0xffff0000u);
  return r;
}

// -------- transpose planes (v,pl,c,y,x) f32 -> (v,pl,y,x,c) bf16 --------
// bf16 halves gather payload: one dwordx4 per tap per lane (was 2).
__global__ __launch_bounds__(PRES) void transpose_planes_bf16(
    const float* __restrict__ in, unsigned short* __restrict__ out) {
  int b  = blockIdx.x;          // vp*256 + y
  int vp = b >> 8;
  int y  = b & 255;
  int x  = threadIdx.x;
  const float* src = in + (size_t)vp * FEATC * PRES * PRES + (size_t)y * PRES + x;
  unsigned short* dst = out + (((size_t)vp * PRES + y) * PRES + x) * FEATC;
  unsigned int v[16];
#pragma unroll
  for (int c = 0; c < 16; ++c) {
    const float lo = src[(size_t)(2 * c) * PRES * PRES];
    const float hi = src[(size_t)(2 * c + 1) * PRES * PRES];
    v[c] = (unsigned int)f2bf(lo) | ((unsigned int)f2bf(hi) << 16);
  }
#pragma unroll
  for (int q = 0; q < 4; ++q)
    *(uint4*)(dst + q * 8) = make_uint4(v[q * 4 + 0], v[q * 4 + 1], v[q * 4 + 2], v[q * 4 + 3]);
}

// -------- waveized render: 1 ray/wave; B-frags in block LDS; bf16 planes --------
// Design ledger (r1-r20):
//  - MFMA for all 4 MLP GEMMs; A-frags gathered directly into registers.
//  - Weight B-frags in a 20KB block-shared LDS table (global frags: r18 REGRESSED).
//  - LDS <= ~69.6KB/block for 2 blocks/CU (r13: 76.2KB -> 1 block/CU).
//  - No wave-internal fences (r13/r17-proven correct, neutral perf).
//  - Scalar b16 epilogue writes (packed-b64 swap: r19 REGRESSED).
//  - r21: planes stored bf16 -> 24 gather VMEM/iter (was 48), attacking the
//    diagnosed memory-transaction bound (all pipes <40%, occupancy-insensitive).
//  - __launch_bounds__(.,4) forces a 64-VGPR cap -> ~1GB spill (r4-r5). Use (.,2).
template <int TR>
__global__ __launch_bounds__(TPB, 2) void render_wave(
    const float* __restrict__ c2w, const float* __restrict__ planes,
    const unsigned short* __restrict__ planesq,
    const float* __restrict__ background, const float* __restrict__ t_jitter,
    const float* __restrict__ W1, const float* __restrict__ b1,
    const float* __restrict__ W2, const float* __restrict__ b2,
    const float* __restrict__ Wr1, const float* __restrict__ br1,
    const float* __restrict__ Wr2, const float* __restrict__ br2,
    float* __restrict__ out) {
  // frag f in [0,20): 0..11 = W1[ks*4+nt]; 12..13 = W2[ks]; 14..17 = R1[nt]; 18..19 = R2[ks]
  __shared__ __bf16 wlds[20 * 64 * 8];      // 20.0 KB block-shared B-frags
  __shared__ __bf16 hbA[NW][32][HPAD2];     // 36.0 KB: h -> colorA(cols0..17) -> hr
  __shared__ float alphaA[NW][96];          // 3.0 KB raw sigma logits
  __shared__ float rgbA[NW][96 * 3];        // 9.0 KB raw rgb logits
  // total 68.0 KB -> 2 blocks/CU

  const int tid = threadIdx.x;
  const int w = tid >> 6;        // wave 0..NW-1
  const int lane = tid & 63;
  const int lr = lane & 15;
  const int lg = lane >> 4;

  __bf16 (*hb)[HPAD2] = hbA[w];
  float* alphaL = alphaA[w];
  float* rgbL = rgbA[w];

  // ---- stage B-fragments into LDS ----
  for (int slot = tid; slot < 20 * 64; slot += TPB) {
    const int f = slot >> 6, l = slot & 63;
    const int flr = l & 15, flg = l >> 4;
    union { unsigned short u[8]; bf16x8 b; } t;
    if (f < 12) {
      const int ks = f >> 2, nt = f & 3;
#pragma unroll
      for (int i = 0; i < 8; ++i)
        t.u[i] = f2bf(W1[(ks * 32 + flg * 8 + i) * 64 + nt * 16 + flr]);
    } else if (f < 14) {
      const int ks = f - 12;
#pragma unroll
      for (int i = 0; i < 8; ++i)
        t.u[i] = f2bf(W2[(ks * 32 + flg * 8 + i) * 16 + flr]);
    } else if (f < 18) {
      const int nt = f - 14;
#pragma unroll
      for (int i = 0; i < 8; ++i) {
        const int k = flg * 8 + i;
        t.u[i] = (k < 18) ? f2bf(Wr1[k * 64 + nt * 16 + flr]) : (unsigned short)0;
      }
    } else {
      const int ks = f - 18;
#pragma unroll
      for (int i = 0; i < 8; ++i)
        t.u[i] = (flr < 3) ? f2bf(Wr2[(ks * 32 + flg * 8 + i) * 3 + flr]) : (unsigned short)0;
    }
    *(bf16x8*)&wlds[slot * 8] = t.b;
  }

  float b1v[4], br1v[4];
#pragma unroll
  for (int nt = 0; nt < 4; ++nt) { b1v[nt] = b1[nt * 16 + lr]; br1v[nt] = br1[nt * 16 + lr]; }
  const float b2v = b2[lr];
  const float br2v = (lr < 3) ? br2[lr] : 0.f;

  // ---- ray setup (wave-uniform) ----
  const int ray = blockIdx.x * NW + w;       // NRAYS % NW == 0: no tail
  const int view = ray >> 12;
  const int p = ray & 4095;
  const float foc = 0.5f * (float)RESN / tanf(FOVF * 0.5f);
  const float dxn = ((float)(p & 63) + 0.5f - 32.f) / foc;
  const float dyn = ((float)(p >> 6) + 0.5f - 32.f) / foc;
  const float* M = c2w + view * 16;
  const float rdx = M[0] * dxn + M[1] * dyn + M[2];
  const float rdy = M[4] * dxn + M[5] * dyn + M[6];
  const float rdz = M[8] * dxn + M[9] * dyn + M[10];
  const float rox = M[3] + 0.5f, roy = M[7] + 0.5f, roz = M[11] + 0.5f;
  const unsigned int dirxy = (unsigned int)f2bf(rdx) | ((unsigned int)f2bf(rdy) << 16);
  const unsigned short dirz = f2bf(rdz);

  __syncthreads();   // weight table ready (only block barrier)

  const __bf16* wl = wlds + lane * 8;   // lane-fixed base; frag f at +f*512 elems

  for (int iter = 0; iter < 3; ++iter) {
    // ---- per-lane positions for its two A-frag rows (m0=lr, m1=lr+16) ----
    float pxr[2], pyr[2], pzr[2];
#pragma unroll
    for (int rowi = 0; rowi < 2; ++rowi) {
      const int s = iter * 32 + lr + rowi * 16;
      const int sj = (s < NSAMP) ? s : (NSAMP - 1);
      const float jit = t_jitter[(size_t)ray * NSAMP + sj];
      const float t = 1.0f + ((float)s + jit) * STEPF + STEPF * 0.5f;
      pxr[rowi] = fminf(fmaxf(rox + rdx * t, 0.f), 1.f);
      pyr[rowi] = fminf(fmaxf(roy + rdy * t, 0.f), 1.f);
      pzr[rowi] = fminf(fmaxf(roz + rdz * t, 0.f), 1.f);
    }

    // ---- build GEMM1 A-frags in registers (bf16 planes: 1 dwordx4 per tap) ----
    bf16x8 fv[3][2];
#pragma unroll
    for (int pl = 0; pl < 3; ++pl) {
#pragma unroll
      for (int rowi = 0; rowi < 2; ++rowi) {
        const float uu = (pl == 2) ? pyr[rowi] : pxr[rowi];
        const float vv = (pl == 0) ? pyr[rowi] : pzr[rowi];
        const float xf = uu * 255.f, yf = vv * 255.f;
        const float x0f = floorf(xf), y0f = floorf(yf);
        const float wx = xf - x0f, wy = yf - y0f;
        const int x0 = (int)x0f, y0 = (int)y0f;
        const int x1 = min(x0 + 1, 255), y1 = min(y0 + 1, 255);
        const float w00 = (1.f - wx) * (1.f - wy), w01 = wx * (1.f - wy);
        const float w10 = (1.f - wx) * wy, w11 = wx * wy;
        f32x2 fp[4];
        if (TR) {
          // bf16 plane elems; uint offsets keep addr math 32-bit
          const unsigned int slab = (unsigned int)(view * 3 + pl) * (PRES * PRES * FEATC);
          const unsigned int o00 = slab + ((unsigned int)(y0 * 256 + x0) << 5) + (lg << 3);
          const unsigned int dx32 = (unsigned int)(x1 - x0) << 5;
          const unsigned int dy32 = (unsigned int)(y1 - y0) << 13;
          const uint4 A = *(const uint4*)(planesq + o00);
          const uint4 B = *(const uint4*)(planesq + (o00 + dx32));
          const uint4 C = *(const uint4*)(planesq + (o00 + dy32));
          const uint4 D = *(const uint4*)(planesq + (o00 + dx32 + dy32));
          fp[0] = bf2f(A.x) * w00 + bf2f(B.x) * w01 + bf2f(C.x) * w10 + bf2f(D.x) * w11;
          fp[1] = bf2f(A.y) * w00 + bf2f(B.y) * w01 + bf2f(C.y) * w10 + bf2f(D.y) * w11;
          fp[2] = bf2f(A.z) * w00 + bf2f(B.z) * w01 + bf2f(C.z) * w10 + bf2f(D.z) * w11;
          fp[3] = bf2f(A.w) * w00 + bf2f(B.w) * w01 + bf2f(C.w) * w10 + bf2f(D.w) * w11;
        } else {
          const float* pb = planes + (size_t)(view * 3 + pl) * (FEATC * PRES * PRES);
          const int o00 = y0 * 256 + x0, o01 = y0 * 256 + x1;
          const int o10 = y1 * 256 + x0, o11 = y1 * 256 + x1;
          float f[8];
#pragma unroll
          for (int c = 0; c < 8; ++c) {
            const float* pc = pb + (size_t)(lg * 8 + c) * (PRES * PRES);
            f[c] = pc[o00] * w00 + pc[o01] * w01 + pc[o10] * w10 + pc[o11] * w11;
          }
#pragma unroll
          for (int j = 0; j < 4; ++j) fp[j] = mk2(f[2 * j], f[2 * j + 1]);
        }
        bf16x8 vfr;
#pragma unroll
        for (int j = 0; j < 4; ++j) { vfr[2 * j] = (__bf16)fp[j][0]; vfr[2 * j + 1] = (__bf16)fp[j][1]; }
        fv[pl][rowi] = vfr;
      }
    }

    // ---- GEMM1 (nt-outer, 8 acc regs): h = relu(feat @ W1 + b1) -> hb cols 0..63 ----
#pragma unroll
    for (int nt = 0; nt < 4; ++nt) {
      f32x4 acc[2] = {};
#pragma unroll
      for (int pl = 0; pl < 3; ++pl) {
        const bf16x8 bw = *(const bf16x8*)(wl + (pl * 4 + nt) * 512);
#pragma unroll
        for (int mt = 0; mt < 2; ++mt)
          acc[mt] = __builtin_amdgcn_mfma_f32_16x16x32_bf16(fv[pl][mt], bw, acc[mt], 0, 0, 0);
      }
#pragma unroll
      for (int mt = 0; mt < 2; ++mt)
#pragma unroll
        for (int r = 0; r < 4; ++r)
          hb[mt * 16 + lg * 4 + r][nt * 16 + lr] = (__bf16)fmaxf(acc[mt][r] + b1v[nt], 0.f);
    }

    // ---- GEMM2: h @ W2 (64->16) ----
    f32x4 acc2[2] = {};
    {
      const bf16x8 bw0 = *(const bf16x8*)(wl + 12 * 512);
      const bf16x8 bw1 = *(const bf16x8*)(wl + 13 * 512);
#pragma unroll
      for (int mt = 0; mt < 2; ++mt) {
        const bf16x8 a0 = *(const bf16x8*)&hb[mt * 16 + lr][lg * 8];
        const bf16x8 a1 = *(const bf16x8*)&hb[mt * 16 + lr][32 + lg * 8];
        acc2[mt] = __builtin_amdgcn_mfma_f32_16x16x32_bf16(a0, bw0, acc2[mt], 0, 0, 0);
        acc2[mt] = __builtin_amdgcn_mfma_f32_16x16x32_bf16(a1, bw1, acc2[mt], 0, 0, 0);
      }
    }
    // epilogue: raw sigma -> alphaL; dir -> hb cols 0..2; geo -> hb cols 3..17
#pragma unroll
    for (int mt = 0; mt < 2; ++mt)
#pragma unroll
      for (int r = 0; r < 4; ++r) {
        const int m = mt * 16 + lg * 4 + r;
        const int s2 = iter * 32 + m;
        const float val = acc2[mt][r] + b2v;
        if (lr == 0) {
          alphaL[s2] = val;
          *(unsigned int*)&hb[m][0] = dirxy;
          *(unsigned short*)&hb[m][2] = dirz;
        } else {
          hb[m][2 + lr] = (__bf16)val;   // geo i=lr-1 -> col 3+(lr-1)
        }
      }

    // ---- GEMM3: colorA[32x32] @ Wr1pad (cols 18..31 stale-h x zero weights) ----
    {
      bf16x8 a[2];
#pragma unroll
      for (int mt = 0; mt < 2; ++mt) a[mt] = *(const bf16x8*)&hb[mt * 16 + lr][lg * 8];
#pragma unroll
      for (int nt = 0; nt < 4; ++nt) {
        const bf16x8 bw = *(const bf16x8*)(wl + (14 + nt) * 512);
        f32x4 acc[2] = {};
#pragma unroll
        for (int mt = 0; mt < 2; ++mt)
          acc[mt] = __builtin_amdgcn_mfma_f32_16x16x32_bf16(a[mt], bw, acc[mt], 0, 0, 0);
#pragma unroll
        for (int mt = 0; mt < 2; ++mt)
#pragma unroll
          for (int r = 0; r < 4; ++r)
            hb[mt * 16 + lg * 4 + r][nt * 16 + lr] = (__bf16)fmaxf(acc[mt][r] + br1v[nt], 0.f);
      }
    }

    // ---- GEMM4: hr @ Wr2pad -> raw rgb logits ----
    f32x4 acc4[2] = {};
    {
      const bf16x8 bw0 = *(const bf16x8*)(wl + 18 * 512);
      const bf16x8 bw1 = *(const bf16x8*)(wl + 19 * 512);
#pragma unroll
      for (int mt = 0; mt < 2; ++mt) {
        const bf16x8 a0 = *(const bf16x8*)&hb[mt * 16 + lr][lg * 8];
        const bf16x8 a1 = *(const bf16x8*)&hb[mt * 16 + lr][32 + lg * 8];
        acc4[mt] = __builtin_amdgcn_mfma_f32_16x16x32_bf16(a0, bw0, acc4[mt], 0, 0, 0);
        acc4[mt] = __builtin_amdgcn_mfma_f32_16x16x32_bf16(a1, bw1, acc4[mt], 0, 0, 0);
      }
    }
#pragma unroll
    for (int mt = 0; mt < 2; ++mt)
#pragma unroll
      for (int r = 0; r < 4; ++r) {
        const int m = mt * 16 + lg * 4 + r;
        const int s2 = iter * 32 + m;
        if (lr < 3) rgbL[s2 * 3 + lr] = acc4[mt][r] + br2v;
      }
  }

  // ---- per-wave composite with inline activations ----
  {
    const float o0 = alphaL[lane];
    const float sp = fmaxf(o0, 0.f) + log1pf(__expf(-fabsf(o0)));
    const float a = 1.f - __expf(-sp * STEPF);
    float r0 = rgbL[lane * 3 + 0], r1 = rgbL[lane * 3 + 1], r2 = rgbL[lane * 3 + 2];
    r0 = 1.f / (1.f + __expf(-r0));
    r1 = 1.f / (1.f + __expf(-r1));
    r2 = 1.f / (1.f + __expf(-r2));
    float q = 1.f - a + 1e-10f;
#pragma unroll
    for (int d = 1; d < 64; d <<= 1) { const float t = __shfl_up(q, d); if (lane >= d) q *= t; }
    float T = __shfl_up(q, 1);
    if (lane == 0) T = 1.f;
    const float wgt = T * a;
    float cr = wgt * r0, cg = wgt * r1, cb = wgt * r2, accA = wgt;
    const float Ttot = __shfl(q, 63);
    float a2 = 0.f, s0 = 0.f, s1 = 0.f, s2c = 0.f;
    if (lane < 28) {
      const int i2 = 64 + lane;
      const float o0b = alphaL[i2];
      const float spb = fmaxf(o0b, 0.f) + log1pf(__expf(-fabsf(o0b)));
      a2 = 1.f - __expf(-spb * STEPF);
      s0 = 1.f / (1.f + __expf(-rgbL[i2 * 3 + 0]));
      s1 = 1.f / (1.f + __expf(-rgbL[i2 * 3 + 1]));
      s2c = 1.f / (1.f + __expf(-rgbL[i2 * 3 + 2]));
    }
    float q2 = 1.f - a2 + 1e-10f;
#pragma unroll
    for (int d = 1; d < 64; d <<= 1) { const float t = __shfl_up(q2, d); if (lane >= d) q2 *= t; }
    float T2 = __shfl_up(q2, 1);
    if (lane == 0) T2 = 1.f;
    T2 *= Ttot;
    if (lane < 28) {
      const float w2 = T2 * a2;
      cr += w2 * s0; cg += w2 * s1; cb += w2 * s2c;
      accA += w2;
    }
#pragma unroll
    for (int d = 32; d; d >>= 1) {
      cr += __shfl_xor(cr, d); cg += __shfl_xor(cg, d);
      cb += __shfl_xor(cb, d); accA += __shfl_xor(accA, d);
    }
    if (lane == 0) {
      const float* bg = background + view * 3;
      float* po = out + (size_t)ray * 3;
      po[0] = cr + (1.f - accA) * bg[0];
      po[1] = cg + (1.f - accA) * bg[1];
      po[2] = cb + (1.f - accA) * bg[2];
    }
  }
}

extern "C" void kernel_launch(void* const* d_in, const int* in_sizes, int n_in,
                              void* d_out, int out_size, void* d_ws, size_t ws_size,
                              hipStream_t stream) {
  const float* c2w        = (const float*)d_in[0];
  const float* planes     = (const float*)d_in[1];
  const float* background = (const float*)d_in[2];
  const float* t_jitter   = (const float*)d_in[3];
  const float* W1  = (const float*)d_in[4];
  const float* b1  = (const float*)d_in[5];
  const float* W2  = (const float*)d_in[6];
  const float* b2  = (const float*)d_in[7];
  const float* Wr1 = (const float*)d_in[8];
  const float* br1 = (const float*)d_in[9];
  const float* Wr2 = (const float*)d_in[10];
  const float* br2 = (const float*)d_in[11];
  float* out = (float*)d_out;

  const int n_blocks = NRAYS / NW;   // 2048 blocks, 1 ray per wave
  const size_t tr_bytes = NPLANE * sizeof(unsigned short);   // bf16 table: 50.3 MB

  if (ws_size >= tr_bytes) {
    unsigned short* tp = (unsigned short*)d_ws;
    transpose_planes_bf16<<<NVIEWS * 3 * PRES, PRES, 0, stream>>>(planes, tp);
    render_wave<1><<<n_blocks, TPB, 0, stream>>>(
        c2w, planes, tp, background, t_jitter, W1, b1, W2, b2, Wr1, br1, Wr2, br2, out);
  } else {
    render_wave<0><<<n_blocks, TPB, 0, stream>>>(
        c2w, planes, nullptr, background, t_jitter, W1, b1, W2, b2, Wr1, br1, Wr2, br2, out);
  }
}